// Round 1
// baseline (299.461 us; speedup 1.0000x reference)
//
#include <hip/hip_runtime.h>
#include <math.h>

// TimestepNorm forward: running Welford mean/var over T, then affine norm.
// Reformulated as prefix sums (coefficients are data-independent):
//   c_t   = C0 + #valid<=t
//   M_t   = C0*pm + sum(valid*x)          -> mean = M/c
//   M2_t  = M2_0 + sum(valid*x^2) + M_0^2/C0 - M_t^2/c_t -> var = M2/c
// 3-kernel chunked scan: partials -> exclusive chunk scan -> replay+epilogue.

#define T_DIM 8192
#define B_DIM 8
#define D_DIM 512
#define NC    128              // chunks along T
#define CT    (T_DIM / NC)     // 64 steps per chunk
#define BD    (B_DIM * D_DIM)  // 4096
#define C0    2.0f             // PRIOR_COUNT
#define EPS   1e-5f

// ws layout (floats):
//   s1p[NC][BD]   chunk partial sums of valid*x
//   s2p[NC][BD]   chunk partial sums of valid*x^2
//   cnt[NC][B]    chunk partial counts of valid steps

__global__ __launch_bounds__(128) void ts_pass1(
    const float* __restrict__ x, const unsigned char* __restrict__ mask,
    float* __restrict__ s1p, float* __restrict__ s2p, float* __restrict__ cnt) {
  const int chunk = blockIdx.x;          // 0..NC-1
  const int b     = blockIdx.y;          // 0..B-1
  const int tid   = threadIdx.x;         // 0..127 -> 4 consecutive d
  const int t0    = chunk * CT;
  const float4* xp = (const float4*)x;
  const unsigned char* mrow = mask + b * T_DIM + t0;

  float s1x = 0.f, s1y = 0.f, s1z = 0.f, s1w = 0.f;
  float s2x = 0.f, s2y = 0.f, s2z = 0.f, s2w = 0.f;
  float c = 0.f;
#pragma unroll 4
  for (int i = 0; i < CT; ++i) {
    float valid = mrow[i] ? 0.f : 1.f;
    float4 v = xp[((t0 + i) * B_DIM + b) * (D_DIM / 4) + tid];
    c += valid;
    s1x += valid * v.x; s2x += valid * v.x * v.x;
    s1y += valid * v.y; s2y += valid * v.y * v.y;
    s1z += valid * v.z; s2z += valid * v.z * v.z;
    s1w += valid * v.w; s2w += valid * v.w * v.w;
  }
  const int pidx = chunk * (BD / 4) + b * (D_DIM / 4) + tid;
  ((float4*)s1p)[pidx] = make_float4(s1x, s1y, s1z, s1w);
  ((float4*)s2p)[pidx] = make_float4(s2x, s2y, s2z, s2w);
  if (tid == 0) cnt[chunk * B_DIM + b] = c;
}

__global__ __launch_bounds__(256) void ts_pass2(
    float* __restrict__ s1p, float* __restrict__ s2p, float* __restrict__ cnt) {
  const int gid = blockIdx.x * 256 + threadIdx.x;  // 0..BD-1, one (b,d) each
  float r1 = 0.f, r2 = 0.f;
#pragma unroll 4
  for (int k = 0; k < NC; ++k) {
    const int idx = k * BD + gid;
    float a1 = s1p[idx], a2 = s2p[idx];
    s1p[idx] = r1; s2p[idx] = r2;
    r1 += a1; r2 += a2;
  }
  if (gid < B_DIM) {          // exclusive scan of per-chunk valid counts
    float rc = 0.f;
    for (int k = 0; k < NC; ++k) {
      float a = cnt[k * B_DIM + gid];
      cnt[k * B_DIM + gid] = rc;
      rc += a;
    }
  }
}

__global__ __launch_bounds__(128) void ts_pass3(
    const float* __restrict__ x, const unsigned char* __restrict__ mask,
    const float* __restrict__ pm, const float* __restrict__ plv,
    const float* __restrict__ w, const float* __restrict__ bias,
    const float* __restrict__ s1p, const float* __restrict__ s2p,
    const float* __restrict__ cnt, float* __restrict__ out) {
  const int chunk = blockIdx.x;
  const int b     = blockIdx.y;
  const int tid   = threadIdx.x;
  const int t0    = chunk * CT;

  float4 pm4 = ((const float4*)pm)[tid];
  float4 lv4 = ((const float4*)plv)[tid];
  float4 g4  = ((const float4*)w)[tid];
  float4 be4 = ((const float4*)bias)[tid];
  g4.x += 1.f; g4.y += 1.f; g4.z += 1.f; g4.w += 1.f;
  // M0 = C0*pm ;  V2 = C0*var0 + M0^2/C0 = C0*(exp(plv) + pm^2)
  float M0x = C0 * pm4.x, M0y = C0 * pm4.y, M0z = C0 * pm4.z, M0w = C0 * pm4.w;
  float V2x = C0 * (__expf(lv4.x) + pm4.x * pm4.x);
  float V2y = C0 * (__expf(lv4.y) + pm4.y * pm4.y);
  float V2z = C0 * (__expf(lv4.z) + pm4.z * pm4.z);
  float V2w = C0 * (__expf(lv4.w) + pm4.w * pm4.w);

  const int pidx = chunk * (BD / 4) + b * (D_DIM / 4) + tid;
  float4 S1 = ((const float4*)s1p)[pidx];
  float4 S2 = ((const float4*)s2p)[pidx];
  float c = C0 + cnt[chunk * B_DIM + b];

  const float4* xp = (const float4*)x;
  float4* op = (float4*)out;
  const unsigned char* mrow = mask + b * T_DIM + t0;

#pragma unroll 4
  for (int i = 0; i < CT; ++i) {
    float valid = mrow[i] ? 0.f : 1.f;
    const int xi = ((t0 + i) * B_DIM + b) * (D_DIM / 4) + tid;
    float4 v = xp[xi];
    c += valid;
    float rc = __builtin_amdgcn_rcpf(c);
    float4 y;
    {
      S1.x += valid * v.x; S2.x += valid * v.x * v.x;
      float M = M0x + S1.x;
      float mean = M * rc;
      float var = (V2x + S2.x - M * M * rc) * rc;
      y.x = (v.x - mean) * __builtin_amdgcn_rsqf(var + EPS) * g4.x + be4.x;
    }
    {
      S1.y += valid * v.y; S2.y += valid * v.y * v.y;
      float M = M0y + S1.y;
      float mean = M * rc;
      float var = (V2y + S2.y - M * M * rc) * rc;
      y.y = (v.y - mean) * __builtin_amdgcn_rsqf(var + EPS) * g4.y + be4.y;
    }
    {
      S1.z += valid * v.z; S2.z += valid * v.z * v.z;
      float M = M0z + S1.z;
      float mean = M * rc;
      float var = (V2z + S2.z - M * M * rc) * rc;
      y.z = (v.z - mean) * __builtin_amdgcn_rsqf(var + EPS) * g4.z + be4.z;
    }
    {
      S1.w += valid * v.w; S2.w += valid * v.w * v.w;
      float M = M0w + S1.w;
      float mean = M * rc;
      float var = (V2w + S2.w - M * M * rc) * rc;
      y.w = (v.w - mean) * __builtin_amdgcn_rsqf(var + EPS) * g4.w + be4.w;
    }
    op[xi] = y;
  }
}

extern "C" void kernel_launch(void* const* d_in, const int* in_sizes, int n_in,
                              void* d_out, int out_size, void* d_ws, size_t ws_size,
                              hipStream_t stream) {
  const float* x    = (const float*)d_in[0];
  const float* pm   = (const float*)d_in[1];
  const float* plv  = (const float*)d_in[2];
  const float* w    = (const float*)d_in[3];
  const float* bias = (const float*)d_in[4];
  const unsigned char* mask = (const unsigned char*)d_in[5];  // jnp bool -> 1 byte
  float* out = (float*)d_out;

  float* s1p = (float*)d_ws;
  float* s2p = s1p + (size_t)NC * BD;
  float* cnt = s2p + (size_t)NC * BD;

  dim3 grid(NC, B_DIM);
  ts_pass1<<<grid, 128, 0, stream>>>(x, mask, s1p, s2p, cnt);
  ts_pass2<<<BD / 256, 256, 0, stream>>>(s1p, s2p, cnt);
  ts_pass3<<<grid, 128, 0, stream>>>(x, mask, pm, plv, w, bias, s1p, s2p, cnt, out);
}

// Round 2
// 291.152 us; speedup vs baseline: 1.0285x; 1.0285x over previous
//
#include <hip/hip_runtime.h>
#include <math.h>

// TimestepNorm forward: running Welford mean/var over T, then affine norm.
// Reformulated as prefix sums (coefficients are data-independent):
//   c_t   = C0 + #valid<=t
//   M_t   = C0*pm + sum(valid*x)          -> mean = M/c
//   var_t = (V2 + sum(valid*x^2) - M_t^2/c_t)/c_t,  V2 = C0*(exp(plv)+pm^2)
// 2-kernel chunked scan: pass1 computes per-chunk partials; pass3 re-derives
// the exclusive chunk prefix itself (8 MB partials are L2/L3-resident, so the
// O(NC^2) re-read is ~free) then replays its chunk with the y epilogue.
// Pass2 (16-block latency-bound scan) is eliminated.

#define T_DIM 8192
#define B_DIM 8
#define D_DIM 512
#define NC    128              // chunks along T
#define CT    (T_DIM / NC)     // 64 steps per chunk
#define BD    (B_DIM * D_DIM)  // 4096
#define C0    2.0f             // PRIOR_COUNT
#define EPS   1e-5f

// ws layout (floats):
//   s1p[NC][BD]   chunk partial sums of valid*x
//   s2p[NC][BD]   chunk partial sums of valid*x^2
//   cnt[NC][B]    chunk partial counts of valid steps

__global__ __launch_bounds__(128) void ts_pass1(
    const float* __restrict__ x, const unsigned char* __restrict__ mask,
    float* __restrict__ s1p, float* __restrict__ s2p, float* __restrict__ cnt) {
  const int chunk = blockIdx.x;          // 0..NC-1
  const int b     = blockIdx.y;          // 0..B-1
  const int tid   = threadIdx.x;         // 0..127 -> 4 consecutive d
  const int t0    = chunk * CT;
  const float4* xp = (const float4*)x;

  // Hoist the 64 mask bytes for this chunk into 8 u64 registers (broadcast
  // loads) instead of 64 per-iteration byte loads.
  unsigned long long mw[CT / 8];
  const unsigned long long* m8 =
      (const unsigned long long*)(mask + b * T_DIM + t0);
#pragma unroll
  for (int j = 0; j < CT / 8; ++j) mw[j] = m8[j];

  float s1x = 0.f, s1y = 0.f, s1z = 0.f, s1w = 0.f;
  float s2x = 0.f, s2y = 0.f, s2z = 0.f, s2w = 0.f;
  float c = 0.f;
#pragma unroll 8
  for (int i = 0; i < CT; ++i) {
    float valid = ((mw[i >> 3] >> ((i & 7) * 8)) & 0xffULL) ? 0.f : 1.f;
    float4 v = xp[((t0 + i) * B_DIM + b) * (D_DIM / 4) + tid];
    c += valid;
    s1x += valid * v.x; s2x += valid * v.x * v.x;
    s1y += valid * v.y; s2y += valid * v.y * v.y;
    s1z += valid * v.z; s2z += valid * v.z * v.z;
    s1w += valid * v.w; s2w += valid * v.w * v.w;
  }
  const int pidx = chunk * (BD / 4) + b * (D_DIM / 4) + tid;
  ((float4*)s1p)[pidx] = make_float4(s1x, s1y, s1z, s1w);
  ((float4*)s2p)[pidx] = make_float4(s2x, s2y, s2z, s2w);
  if (tid == 0) cnt[chunk * B_DIM + b] = c;
}

__global__ __launch_bounds__(128) void ts_pass3(
    const float* __restrict__ x, const unsigned char* __restrict__ mask,
    const float* __restrict__ pm, const float* __restrict__ plv,
    const float* __restrict__ w, const float* __restrict__ bias,
    const float* __restrict__ s1p, const float* __restrict__ s2p,
    const float* __restrict__ cnt, float* __restrict__ out) {
  const int chunk = blockIdx.x;
  const int b     = blockIdx.y;
  const int tid   = threadIdx.x;
  const int t0    = chunk * CT;

  // ---- exclusive chunk prefix, computed in-block (replaces old pass2) ----
  float4 S1 = make_float4(0.f, 0.f, 0.f, 0.f);
  float4 S2 = make_float4(0.f, 0.f, 0.f, 0.f);
  float csum = 0.f;
  {
    const float4* p1 = (const float4*)s1p;
    const float4* p2 = (const float4*)s2p;
    const int col = b * (D_DIM / 4) + tid;
#pragma unroll 4
    for (int k = 0; k < chunk; ++k) {
      float4 a1 = p1[k * (BD / 4) + col];
      float4 a2 = p2[k * (BD / 4) + col];
      S1.x += a1.x; S1.y += a1.y; S1.z += a1.z; S1.w += a1.w;
      S2.x += a2.x; S2.y += a2.y; S2.z += a2.z; S2.w += a2.w;
      csum += cnt[k * B_DIM + b];   // uniform -> broadcast load
    }
  }
  float c = C0 + csum;

  float4 pm4 = ((const float4*)pm)[tid];
  float4 lv4 = ((const float4*)plv)[tid];
  float4 g4  = ((const float4*)w)[tid];
  float4 be4 = ((const float4*)bias)[tid];
  g4.x += 1.f; g4.y += 1.f; g4.z += 1.f; g4.w += 1.f;
  // M0 = C0*pm ;  V2 = C0*var0 + M0^2/C0 = C0*(exp(plv) + pm^2)
  float M0x = C0 * pm4.x, M0y = C0 * pm4.y, M0z = C0 * pm4.z, M0w = C0 * pm4.w;
  float V2x = C0 * (__expf(lv4.x) + pm4.x * pm4.x);
  float V2y = C0 * (__expf(lv4.y) + pm4.y * pm4.y);
  float V2z = C0 * (__expf(lv4.z) + pm4.z * pm4.z);
  float V2w = C0 * (__expf(lv4.w) + pm4.w * pm4.w);

  unsigned long long mw[CT / 8];
  const unsigned long long* m8 =
      (const unsigned long long*)(mask + b * T_DIM + t0);
#pragma unroll
  for (int j = 0; j < CT / 8; ++j) mw[j] = m8[j];

  const float4* xp = (const float4*)x;
  float4* op = (float4*)out;

#pragma unroll 4
  for (int i = 0; i < CT; ++i) {
    float valid = ((mw[i >> 3] >> ((i & 7) * 8)) & 0xffULL) ? 0.f : 1.f;
    const int xi = ((t0 + i) * B_DIM + b) * (D_DIM / 4) + tid;
    float4 v = xp[xi];
    c += valid;
    float rc = __builtin_amdgcn_rcpf(c);
    float4 y;
    {
      S1.x += valid * v.x; S2.x += valid * v.x * v.x;
      float M = M0x + S1.x;
      float mean = M * rc;
      float var = (V2x + S2.x - M * M * rc) * rc;
      y.x = (v.x - mean) * __builtin_amdgcn_rsqf(var + EPS) * g4.x + be4.x;
    }
    {
      S1.y += valid * v.y; S2.y += valid * v.y * v.y;
      float M = M0y + S1.y;
      float mean = M * rc;
      float var = (V2y + S2.y - M * M * rc) * rc;
      y.y = (v.y - mean) * __builtin_amdgcn_rsqf(var + EPS) * g4.y + be4.y;
    }
    {
      S1.z += valid * v.z; S2.z += valid * v.z * v.z;
      float M = M0z + S1.z;
      float mean = M * rc;
      float var = (V2z + S2.z - M * M * rc) * rc;
      y.z = (v.z - mean) * __builtin_amdgcn_rsqf(var + EPS) * g4.z + be4.z;
    }
    {
      S1.w += valid * v.w; S2.w += valid * v.w * v.w;
      float M = M0w + S1.w;
      float mean = M * rc;
      float var = (V2w + S2.w - M * M * rc) * rc;
      y.w = (v.w - mean) * __builtin_amdgcn_rsqf(var + EPS) * g4.w + be4.w;
    }
    op[xi] = y;
  }
}

extern "C" void kernel_launch(void* const* d_in, const int* in_sizes, int n_in,
                              void* d_out, int out_size, void* d_ws, size_t ws_size,
                              hipStream_t stream) {
  const float* x    = (const float*)d_in[0];
  const float* pm   = (const float*)d_in[1];
  const float* plv  = (const float*)d_in[2];
  const float* w    = (const float*)d_in[3];
  const float* bias = (const float*)d_in[4];
  const unsigned char* mask = (const unsigned char*)d_in[5];  // jnp bool -> 1 byte
  float* out = (float*)d_out;

  float* s1p = (float*)d_ws;
  float* s2p = s1p + (size_t)NC * BD;
  float* cnt = s2p + (size_t)NC * BD;

  dim3 grid(NC, B_DIM);
  ts_pass1<<<grid, 128, 0, stream>>>(x, mask, s1p, s2p, cnt);
  ts_pass3<<<grid, 128, 0, stream>>>(x, mask, pm, plv, w, bias, s1p, s2p, cnt, out);
}